// Round 15
// baseline (186.587 us; speedup 1.0000x reference)
//
#include <hip/hip_runtime.h>

// Problem constants: B=1, N=16, T=2048, E=64, H=4, D=16
#define N_ 16
#define T_ 2048
#define E_ 64
#define H_ 4
#define D_ 16
#define NH_ 64            // N_*H_
#define SEXP_ 0.18033688f // 0.125 * log2(e):  exp(s/8) == exp2(s*SEXP_)

typedef __attribute__((ext_vector_type(4))) _Float16 h4;
typedef __attribute__((ext_vector_type(8))) _Float16 h8;
typedef __attribute__((ext_vector_type(2))) __fp16 g2;
typedef __attribute__((ext_vector_type(4))) float f4;

#if __has_builtin(__builtin_amdgcn_exp2f)
__device__ inline float fast_exp2(float x) { return __builtin_amdgcn_exp2f(x); }
#else
__device__ inline float fast_exp2(float x) {
    float r; asm("v_exp_f32 %0, %1" : "=v"(r) : "v"(x)); return r;
}
#endif

__device__ inline h4 pack4_f16(float a, float b, float c, float d) {
    union { g2 g[2]; h4 h; } u;
    u.g[0] = __builtin_amdgcn_cvt_pkrtz(a, b);
    u.g[1] = __builtin_amdgcn_cvt_pkrtz(c, d);
    return u.h;
}

// ---------------------------------------------------------------------------
// K1: fused projections (y=0 Q pre-scaled, y=1 K, y=2 V-transposed, y=3 Wfc^T)
// ---------------------------------------------------------------------------
__global__ __launch_bounds__(256) void proj_kernel(
    const float* __restrict__ xq, const float* __restrict__ Wq, const float* __restrict__ bq,
    const float* __restrict__ xk, const float* __restrict__ Wk, const float* __restrict__ bk,
    const float* __restrict__ xv, const float* __restrict__ Wv, const float* __restrict__ bv,
    const float* __restrict__ Wfc,
    _Float16* __restrict__ Qh, _Float16* __restrict__ Kh, _Float16* __restrict__ Vt,
    _Float16* __restrict__ Wt)
{
    int tid = threadIdx.x;
    int y = blockIdx.y;
    if (y == 3) {
        if (blockIdx.x < 16) {
            int k = blockIdx.x * 4 + (tid >> 6);
            int e = tid & 63;
            Wt[e * 64 + k] = (_Float16)Wfc[k * 64 + e];
        }
        return;
    }
    const float* x = (y == 0) ? xq : (y == 1) ? xk : xv;
    const float* W = (y == 0) ? Wq : (y == 1) ? Wk : Wv;
    const float* b = (y == 0) ? bq : (y == 1) ? bk : bv;
    const float sc = (y == 0) ? SEXP_ : 1.0f;

    __shared__ float Wl[D_ * D_];
    __shared__ float bl[D_];
    Wl[tid] = W[tid];
    if (tid < D_) bl[tid] = b[tid];
    __syncthreads();

    int r = blockIdx.x * 256 + tid;
    int h, t, n;
    if (y == 2) {          // t fastest: coalesced transposed stores
        t = r & (T_ - 1);
        h = (r >> 11) & (H_ - 1);
        n = r >> 13;
    } else {               // h fastest: coalesced reads
        h = r & (H_ - 1);
        t = (r >> 2) & (T_ - 1);
        n = r >> 13;
    }

    const float4* xp4 = reinterpret_cast<const float4*>(
        x + ((size_t)(n * T_ + t) * E_ + h * D_));
    float xv_[D_];
#pragma unroll
    for (int i = 0; i < 4; i++) {
        float4 v = xp4[i];
        xv_[4*i] = v.x; xv_[4*i+1] = v.y; xv_[4*i+2] = v.z; xv_[4*i+3] = v.w;
    }
    float acc[D_];
#pragma unroll
    for (int i = 0; i < D_; i++) acc[i] = bl[i];
#pragma unroll
    for (int j = 0; j < D_; j++) {
        float xj = xv_[j];
#pragma unroll
        for (int i = 0; i < D_; i++) acc[i] = fmaf(xj, Wl[j * D_ + i], acc[i]);
    }
    if (y == 2) {
        _Float16* vb = Vt + (size_t)(n * H_ + h) * D_ * T_ + t;
#pragma unroll
        for (int d = 0; d < D_; d++) vb[(size_t)d * T_] = (_Float16)acc[d];
    } else {
        _Float16 ob[16];
#pragma unroll
        for (int i = 0; i < D_; i++) ob[i] = (_Float16)(acc[i] * sc);
        _Float16* o = (y == 0) ? Qh : Kh;
        uint4* dst = reinterpret_cast<uint4*>(o + (size_t)((n * H_ + h) * T_ + t) * D_);
        dst[0] = reinterpret_cast<uint4*>(ob)[0];
        dst[1] = reinterpret_cast<uint4*>(ob)[1];
    }
}

// ---------------------------------------------------------------------------
// K2: stats — partial column sums Lp[z][nh][k] (R13-exact).
//     4 k-tiles/wave, q-split x4.  grid (NH, 8, 4) x 256.
// ---------------------------------------------------------------------------
__global__ __launch_bounds__(256) void stats_kernel(
    const _Float16* __restrict__ Qh, const _Float16* __restrict__ Kh,
    float* __restrict__ Lp)
{
    int tid = threadIdx.x;
    int lane = tid & 63, wave = tid >> 6;
    int row = lane & 15, quad = lane >> 4;
    int nh = blockIdx.x;
    int kt0 = (blockIdx.y * 4 + wave) * 4;    // first of 4 k-tiles
    int z = blockIdx.z;
    const _Float16* Kb = Kh + (size_t)nh * T_ * D_;
    const _Float16* Qb = Qh + (size_t)nh * T_ * D_;

    h4 a[4];
#pragma unroll
    for (int j = 0; j < 4; j++)
        a[j] = *reinterpret_cast<const h4*>(Kb + ((kt0 + j) * 16 + row) * D_ + quad * 4);

    f4 l[4];
#pragma unroll
    for (int j = 0; j < 4; j++) l[j] = (f4){0.f, 0.f, 0.f, 0.f};
    f4 z4 = {0.f, 0.f, 0.f, 0.f};

    int q_lo = z * (T_ / 4), q_hi = q_lo + T_ / 4;
#pragma unroll 4
    for (int q0 = q_lo; q0 < q_hi; q0 += 16) {
        h4 b = *reinterpret_cast<const h4*>(Qb + (q0 + row) * D_ + quad * 4);
#pragma unroll
        for (int j = 0; j < 4; j++) {
            f4 s = __builtin_amdgcn_mfma_f32_16x16x16f16(a[j], b, z4, 0, 0, 0);
#pragma unroll
            for (int i = 0; i < 4; i++) l[j][i] += fast_exp2(s[i]);
        }
    }
#pragma unroll
    for (int off = 1; off < 16; off <<= 1)
#pragma unroll
        for (int j = 0; j < 4; j++)
#pragma unroll
            for (int i = 0; i < 4; i++)
                l[j][i] += __shfl_xor(l[j][i], off, 64);

    if (row == 0) {
        float* lp = Lp + ((size_t)z * NH_ + nh) * T_;
#pragma unroll
        for (int j = 0; j < 4; j++)
            *reinterpret_cast<f4*>(lp + (kt0 + j) * 16 + quad * 4) = l[j];
    }
}

// ---------------------------------------------------------------------------
// K3: attn — rl prologue (fp16, LDS; combine fused) + k-split x4 PV.
//     2 q-tiles/wave, grid (NH, 16, 4) x 256 -> 4096 blocks, 2x wave
//     oversubscription to saturate the v_exp trans pipe (R13 stalls 32%
//     at 2048 blocks).  Same math as R13 (proven absmax 1.95e-3).
// ---------------------------------------------------------------------------
__global__ __launch_bounds__(256) void attn_kernel(
    const _Float16* __restrict__ Qh, const _Float16* __restrict__ Kh,
    const _Float16* __restrict__ Vt, const float* __restrict__ Lp,
    float* __restrict__ PO)
{
    __shared__ __align__(16) _Float16 rlh[512];
    int tid = threadIdx.x;
    int lane = tid & 63, wave = tid >> 6;
    int row = lane & 15, quad = lane >> 4;
    int nh = blockIdx.x;
    int qt0 = (blockIdx.y * 4 + wave) * 2;    // first of 2 q-tiles
    int z = blockIdx.z;
    int k_lo = z * (T_ / 4);

    // prologue: rlh[i] = fp16( 1 / sum_zz Lp[zz][nh][k_lo+i] ),  i in [0,512)
    {
        int kk = tid * 2;
        float s0 = 0.f, s1 = 0.f;
#pragma unroll
        for (int zz = 0; zz < 4; zz++) {
            float2 lv = *reinterpret_cast<const float2*>(
                Lp + ((size_t)zz * NH_ + nh) * T_ + k_lo + kk);
            s0 += lv.x; s1 += lv.y;
        }
        g2 pk = __builtin_amdgcn_cvt_pkrtz(1.0f / s0, 1.0f / s1);
        *reinterpret_cast<g2*>(&rlh[kk]) = pk;
    }
    __syncthreads();

    const _Float16* Kb = Kh + (size_t)nh * T_ * D_;
    const _Float16* Qb = Qh + (size_t)nh * T_ * D_;
    const _Float16* Vb = Vt + (size_t)nh * D_ * T_ + (size_t)row * T_;

    h4 b[2];
#pragma unroll
    for (int j = 0; j < 2; j++)
        b[j] = *reinterpret_cast<const h4*>(Qb + ((qt0 + j) * 16 + row) * D_ + quad * 4);

    f4 o[2];
#pragma unroll
    for (int j = 0; j < 2; j++) o[j] = (f4){0.f, 0.f, 0.f, 0.f};
    f4 z4 = {0.f, 0.f, 0.f, 0.f};

    int pr = ((row & 12) << 1) | (row & 3);   // permuted K-row offset

    int k_hi = k_lo + T_ / 4;
#pragma unroll 2
    for (int k0 = k_lo; k0 < k_hi; k0 += 32) {
        h4 a0 = *reinterpret_cast<const h4*>(Kb + (k0 + pr) * D_ + quad * 4);
        h4 a1 = *reinterpret_cast<const h4*>(Kb + (k0 + pr + 4) * D_ + quad * 4);
        h8 v = *reinterpret_cast<const h8*>(Vb + k0 + quad * 8);
        h8 rv = *reinterpret_cast<const h8*>(&rlh[(k0 - k_lo) + quad * 8]);
        v = v * rv;                            // fold 1/l into V fragment
#pragma unroll
        for (int j = 0; j < 2; j++) {
            f4 s0 = __builtin_amdgcn_mfma_f32_16x16x16f16(a0, b[j], z4, 0, 0, 0);
            f4 s1 = __builtin_amdgcn_mfma_f32_16x16x16f16(a1, b[j], z4, 0, 0, 0);
            union { h4 h[2]; h8 h8v; } p;
            p.h[0] = pack4_f16(fast_exp2(s0[0]), fast_exp2(s0[1]),
                               fast_exp2(s0[2]), fast_exp2(s0[3]));
            p.h[1] = pack4_f16(fast_exp2(s1[0]), fast_exp2(s1[1]),
                               fast_exp2(s1[2]), fast_exp2(s1[3]));
            o[j] = __builtin_amdgcn_mfma_f32_16x16x32_f16(p.h8v, v, o[j], 0, 0, 0);
        }
    }
    int n = nh >> 2, h = nh & 3;
    float* po = PO + (size_t)z * N_ * T_ * E_ + (size_t)n * T_ * E_ + h * D_ + row;
#pragma unroll
    for (int j = 0; j < 2; j++)
#pragma unroll
        for (int i = 0; i < 4; i++) {
            int q0 = (qt0 + j) * 16 + quad * 4 + i;
            po[(size_t)q0 * E_] = o[j][i];
        }
}

// ---------------------------------------------------------------------------
// K4: fc — out = (sum_z PO[z]) @ Wfc + bfc via 16x16x32 MFMA on Wt.
//     wave: one 16-row M-tile; 2048 tiles -> 512 blocks.
// ---------------------------------------------------------------------------
__global__ __launch_bounds__(256) void fc_kernel(
    const float* __restrict__ PO, const _Float16* __restrict__ Wt,
    const float* __restrict__ bfc, float* __restrict__ out)
{
    int tid = threadIdx.x;
    int lane = tid & 63, wave = tid >> 6;
    int row = lane & 15, quad = lane >> 4;
    int g = blockIdx.x * 4 + wave;             // M-tile id, 2048 total
    int r0 = g * 16;
    size_t base = (size_t)(r0 + row) * E_;
    const size_t zstride = (size_t)N_ * T_ * E_ / 4;   // f4 units

    h8 a[2];
#pragma unroll
    for (int half = 0; half < 2; half++) {
        f4 u0 = {0.f,0.f,0.f,0.f}, u1 = {0.f,0.f,0.f,0.f};
#pragma unroll
        for (int zz = 0; zz < 4; zz++) {
            const f4* p = reinterpret_cast<const f4*>(PO) + zz * zstride + base / 4;
            f4 w0 = p[half * 8 + quad * 2];
            f4 w1 = p[half * 8 + quad * 2 + 1];
#pragma unroll
            for (int i = 0; i < 4; i++) { u0[i] += w0[i]; u1[i] += w1[i]; }
        }
        union { h4 h[2]; h8 v; } pk;
        pk.h[0] = pack4_f16(u0[0], u0[1], u0[2], u0[3]);
        pk.h[1] = pack4_f16(u1[0], u1[1], u1[2], u1[3]);
        a[half] = pk.v;
    }
    f4 acc[4];
#pragma unroll
    for (int ne = 0; ne < 4; ne++) {
        const _Float16* wtb = Wt + (size_t)(ne * 16 + row) * 64;
        h8 b0 = *reinterpret_cast<const h8*>(wtb + quad * 8);
        h8 b1 = *reinterpret_cast<const h8*>(wtb + 32 + quad * 8);
        acc[ne] = __builtin_amdgcn_mfma_f32_16x16x32_f16(a[0], b0, (f4){0.f,0.f,0.f,0.f}, 0, 0, 0);
        acc[ne] = __builtin_amdgcn_mfma_f32_16x16x32_f16(a[1], b1, acc[ne], 0, 0, 0);
    }
#pragma unroll
    for (int ne = 0; ne < 4; ne++) {
        float bias = bfc[ne * 16 + row];
#pragma unroll
        for (int i = 0; i < 4; i++)
            out[(size_t)(r0 + quad * 4 + i) * E_ + ne * 16 + row] = acc[ne][i] + bias;
    }
}

extern "C" void kernel_launch(void* const* d_in, const int* in_sizes, int n_in,
                              void* d_out, int out_size, void* d_ws, size_t ws_size,
                              hipStream_t stream) {
    (void)in_sizes; (void)n_in; (void)out_size; (void)ws_size;
    const float* value = (const float*)d_in[0];
    const float* key   = (const float*)d_in[1];
    const float* query = (const float*)d_in[2];
    const float* Wq    = (const float*)d_in[3];
    const float* bq    = (const float*)d_in[4];
    const float* Wk    = (const float*)d_in[5];
    const float* bk    = (const float*)d_in[6];
    const float* Wv    = (const float*)d_in[7];
    const float* bv    = (const float*)d_in[8];
    const float* Wfc   = (const float*)d_in[9];
    const float* bfc   = (const float*)d_in[10];
    float* out = (float*)d_out;

    // ws bytes: Qh 0-4M | Kh 4-8M | Vt 8-12M | Wt 12M | Lp 13-15M | PO 15-47M
    char* ws = (char*)d_ws;
    _Float16* Qh  = (_Float16*)(ws);
    _Float16* Kh  = (_Float16*)(ws + (4u << 20));
    _Float16* Vt  = (_Float16*)(ws + (8u << 20));
    _Float16* Wt  = (_Float16*)(ws + (12u << 20));
    float*    Lp  = (float*)   (ws + (13u << 20));
    float*    PO  = (float*)   (ws + (15u << 20));

    proj_kernel<<<dim3(512, 4), 256, 0, stream>>>(
        query, Wq, bq, key, Wk, bk, value, Wv, bv, Wfc, Qh, Kh, Vt, Wt);
    stats_kernel<<<dim3(NH_, 8, 4), 256, 0, stream>>>(Qh, Kh, Lp);
    attn_kernel<<<dim3(NH_, 16, 4), 256, 0, stream>>>(Qh, Kh, Vt, Lp, PO);
    fc_kernel<<<512, 256, 0, stream>>>(PO, Wt, bfc, out);
}

// Round 16
// 175.162 us; speedup vs baseline: 1.0652x; 1.0652x over previous
//
#include <hip/hip_runtime.h>

// Problem constants: B=1, N=16, T=2048, E=64, H=4, D=16
#define N_ 16
#define T_ 2048
#define E_ 64
#define H_ 4
#define D_ 16
#define NH_ 64            // N_*H_
#define SEXP_ 0.18033688f // 0.125 * log2(e):  exp(s/8) == exp2(s*SEXP_)

typedef __attribute__((ext_vector_type(4))) _Float16 h4;
typedef __attribute__((ext_vector_type(8))) _Float16 h8;
typedef __attribute__((ext_vector_type(2))) __fp16 g2;
typedef __attribute__((ext_vector_type(4))) float f4;

#if __has_builtin(__builtin_amdgcn_exp2f)
__device__ inline float fast_exp2(float x) { return __builtin_amdgcn_exp2f(x); }
#else
__device__ inline float fast_exp2(float x) {
    float r; asm("v_exp_f32 %0, %1" : "=v"(r) : "v"(x)); return r;
}
#endif

__device__ inline h4 pack4_f16(float a, float b, float c, float d) {
    union { g2 g[2]; h4 h; } u;
    u.g[0] = __builtin_amdgcn_cvt_pkrtz(a, b);
    u.g[1] = __builtin_amdgcn_cvt_pkrtz(c, d);
    return u.h;
}

// ---------------------------------------------------------------------------
// K1: fused projections (y=0 Q pre-scaled, y=1 K, y=2 V-transposed, y=3 Wfc^T)
// ---------------------------------------------------------------------------
__global__ __launch_bounds__(256) void proj_kernel(
    const float* __restrict__ xq, const float* __restrict__ Wq, const float* __restrict__ bq,
    const float* __restrict__ xk, const float* __restrict__ Wk, const float* __restrict__ bk,
    const float* __restrict__ xv, const float* __restrict__ Wv, const float* __restrict__ bv,
    const float* __restrict__ Wfc,
    _Float16* __restrict__ Qh, _Float16* __restrict__ Kh, _Float16* __restrict__ Vt,
    _Float16* __restrict__ Wt)
{
    int tid = threadIdx.x;
    int y = blockIdx.y;
    if (y == 3) {
        if (blockIdx.x < 16) {
            int k = blockIdx.x * 4 + (tid >> 6);
            int e = tid & 63;
            Wt[e * 64 + k] = (_Float16)Wfc[k * 64 + e];
        }
        return;
    }
    const float* x = (y == 0) ? xq : (y == 1) ? xk : xv;
    const float* W = (y == 0) ? Wq : (y == 1) ? Wk : Wv;
    const float* b = (y == 0) ? bq : (y == 1) ? bk : bv;
    const float sc = (y == 0) ? SEXP_ : 1.0f;

    __shared__ float Wl[D_ * D_];
    __shared__ float bl[D_];
    Wl[tid] = W[tid];
    if (tid < D_) bl[tid] = b[tid];
    __syncthreads();

    int r = blockIdx.x * 256 + tid;
    int h, t, n;
    if (y == 2) {          // t fastest: coalesced transposed stores
        t = r & (T_ - 1);
        h = (r >> 11) & (H_ - 1);
        n = r >> 13;
    } else {               // h fastest: coalesced reads
        h = r & (H_ - 1);
        t = (r >> 2) & (T_ - 1);
        n = r >> 13;
    }

    const float4* xp4 = reinterpret_cast<const float4*>(
        x + ((size_t)(n * T_ + t) * E_ + h * D_));
    float xv_[D_];
#pragma unroll
    for (int i = 0; i < 4; i++) {
        float4 v = xp4[i];
        xv_[4*i] = v.x; xv_[4*i+1] = v.y; xv_[4*i+2] = v.z; xv_[4*i+3] = v.w;
    }
    float acc[D_];
#pragma unroll
    for (int i = 0; i < D_; i++) acc[i] = bl[i];
#pragma unroll
    for (int j = 0; j < D_; j++) {
        float xj = xv_[j];
#pragma unroll
        for (int i = 0; i < D_; i++) acc[i] = fmaf(xj, Wl[j * D_ + i], acc[i]);
    }
    if (y == 2) {
        _Float16* vb = Vt + (size_t)(n * H_ + h) * D_ * T_ + t;
#pragma unroll
        for (int d = 0; d < D_; d++) vb[(size_t)d * T_] = (_Float16)acc[d];
    } else {
        _Float16 ob[16];
#pragma unroll
        for (int i = 0; i < D_; i++) ob[i] = (_Float16)(acc[i] * sc);
        _Float16* o = (y == 0) ? Qh : Kh;
        uint4* dst = reinterpret_cast<uint4*>(o + (size_t)((n * H_ + h) * T_ + t) * D_);
        dst[0] = reinterpret_cast<uint4*>(ob)[0];
        dst[1] = reinterpret_cast<uint4*>(ob)[1];
    }
}

// ---------------------------------------------------------------------------
// K2: stats — partial column sums Lp[z][nh][k] = sum_{q in z-chunk} exp2(S')
//     4 k-tiles/wave, q-split x4.  grid (NH, 8, 4) x 256.
// ---------------------------------------------------------------------------
__global__ __launch_bounds__(256) void stats_kernel(
    const _Float16* __restrict__ Qh, const _Float16* __restrict__ Kh,
    float* __restrict__ Lp)
{
    int tid = threadIdx.x;
    int lane = tid & 63, wave = tid >> 6;
    int row = lane & 15, quad = lane >> 4;
    int nh = blockIdx.x;
    int kt0 = (blockIdx.y * 4 + wave) * 4;    // first of 4 k-tiles
    int z = blockIdx.z;
    const _Float16* Kb = Kh + (size_t)nh * T_ * D_;
    const _Float16* Qb = Qh + (size_t)nh * T_ * D_;

    h4 a[4];
#pragma unroll
    for (int j = 0; j < 4; j++)
        a[j] = *reinterpret_cast<const h4*>(Kb + ((kt0 + j) * 16 + row) * D_ + quad * 4);

    f4 l[4];
#pragma unroll
    for (int j = 0; j < 4; j++) l[j] = (f4){0.f, 0.f, 0.f, 0.f};
    f4 z4 = {0.f, 0.f, 0.f, 0.f};

    int q_lo = z * (T_ / 4), q_hi = q_lo + T_ / 4;
#pragma unroll 4
    for (int q0 = q_lo; q0 < q_hi; q0 += 16) {
        h4 b = *reinterpret_cast<const h4*>(Qb + (q0 + row) * D_ + quad * 4);
#pragma unroll
        for (int j = 0; j < 4; j++) {
            f4 s = __builtin_amdgcn_mfma_f32_16x16x16f16(a[j], b, z4, 0, 0, 0);
#pragma unroll
            for (int i = 0; i < 4; i++) l[j][i] += fast_exp2(s[i]);
        }
    }
#pragma unroll
    for (int off = 1; off < 16; off <<= 1)
#pragma unroll
        for (int j = 0; j < 4; j++)
#pragma unroll
            for (int i = 0; i < 4; i++)
                l[j][i] += __shfl_xor(l[j][i], off, 64);

    if (row == 0) {
        float* lp = Lp + ((size_t)z * NH_ + nh) * T_;
#pragma unroll
        for (int j = 0; j < 4; j++)
            *reinterpret_cast<f4*>(lp + (kt0 + j) * 16 + quad * 4) = l[j];
    }
}

// ---------------------------------------------------------------------------
// K3: attn — rl prologue (fp16, LDS; combine fused) + k-split x4 PV.
//     4 q-tiles/wave (measured optimum: 2t=62us, 4t=47us, 8t=48us).
//     Per 32-k: two k16 S-MFMAs with PERMUTED K rows -> A-frag of 16x16x32 PV.
//     V scaled in-register by rlh.  grid (NH, 8, 4) x 256.
// ---------------------------------------------------------------------------
__global__ __launch_bounds__(256) void attn_kernel(
    const _Float16* __restrict__ Qh, const _Float16* __restrict__ Kh,
    const _Float16* __restrict__ Vt, const float* __restrict__ Lp,
    float* __restrict__ PO)
{
    __shared__ __align__(16) _Float16 rlh[512];
    int tid = threadIdx.x;
    int lane = tid & 63, wave = tid >> 6;
    int row = lane & 15, quad = lane >> 4;
    int nh = blockIdx.x;
    int qt0 = (blockIdx.y * 4 + wave) * 4;    // first of 4 q-tiles
    int z = blockIdx.z;
    int k_lo = z * (T_ / 4);

    // prologue: rlh[i] = fp16( 1 / sum_zz Lp[zz][nh][k_lo+i] ),  i in [0,512)
    {
        int kk = tid * 2;
        float s0 = 0.f, s1 = 0.f;
#pragma unroll
        for (int zz = 0; zz < 4; zz++) {
            float2 lv = *reinterpret_cast<const float2*>(
                Lp + ((size_t)zz * NH_ + nh) * T_ + k_lo + kk);
            s0 += lv.x; s1 += lv.y;
        }
        g2 pk = __builtin_amdgcn_cvt_pkrtz(1.0f / s0, 1.0f / s1);
        *reinterpret_cast<g2*>(&rlh[kk]) = pk;
    }
    __syncthreads();

    const _Float16* Kb = Kh + (size_t)nh * T_ * D_;
    const _Float16* Qb = Qh + (size_t)nh * T_ * D_;
    const _Float16* Vb = Vt + (size_t)nh * D_ * T_ + (size_t)row * T_;

    h4 b[4];
#pragma unroll
    for (int j = 0; j < 4; j++)
        b[j] = *reinterpret_cast<const h4*>(Qb + ((qt0 + j) * 16 + row) * D_ + quad * 4);

    f4 o[4];
#pragma unroll
    for (int j = 0; j < 4; j++) o[j] = (f4){0.f, 0.f, 0.f, 0.f};
    f4 z4 = {0.f, 0.f, 0.f, 0.f};

    int pr = ((row & 12) << 1) | (row & 3);   // permuted K-row offset

    int k_hi = k_lo + T_ / 4;
#pragma unroll 2
    for (int k0 = k_lo; k0 < k_hi; k0 += 32) {
        h4 a0 = *reinterpret_cast<const h4*>(Kb + (k0 + pr) * D_ + quad * 4);
        h4 a1 = *reinterpret_cast<const h4*>(Kb + (k0 + pr + 4) * D_ + quad * 4);
        h8 v = *reinterpret_cast<const h8*>(Vb + k0 + quad * 8);
        h8 rv = *reinterpret_cast<const h8*>(&rlh[(k0 - k_lo) + quad * 8]);
        v = v * rv;                            // fold 1/l into V fragment
#pragma unroll
        for (int j = 0; j < 4; j++) {
            f4 s0 = __builtin_amdgcn_mfma_f32_16x16x16f16(a0, b[j], z4, 0, 0, 0);
            f4 s1 = __builtin_amdgcn_mfma_f32_16x16x16f16(a1, b[j], z4, 0, 0, 0);
            union { h4 h[2]; h8 h8v; } p;
            p.h[0] = pack4_f16(fast_exp2(s0[0]), fast_exp2(s0[1]),
                               fast_exp2(s0[2]), fast_exp2(s0[3]));
            p.h[1] = pack4_f16(fast_exp2(s1[0]), fast_exp2(s1[1]),
                               fast_exp2(s1[2]), fast_exp2(s1[3]));
            o[j] = __builtin_amdgcn_mfma_f32_16x16x32_f16(p.h8v, v, o[j], 0, 0, 0);
        }
    }
    int n = nh >> 2, h = nh & 3;
    float* po = PO + (size_t)z * N_ * T_ * E_ + (size_t)n * T_ * E_ + h * D_ + row;
#pragma unroll
    for (int j = 0; j < 4; j++)
#pragma unroll
        for (int i = 0; i < 4; i++) {
            int q0 = (qt0 + j) * 16 + quad * 4 + i;
            po[(size_t)q0 * E_] = o[j][i];
        }
}

// ---------------------------------------------------------------------------
// K4: fc — out = (sum_z PO[z]) @ Wfc + bfc via 16x16x32 MFMA on Wt.
//     wave: one 16-row M-tile; 2048 tiles -> 512 blocks.
// ---------------------------------------------------------------------------
__global__ __launch_bounds__(256) void fc_kernel(
    const float* __restrict__ PO, const _Float16* __restrict__ Wt,
    const float* __restrict__ bfc, float* __restrict__ out)
{
    int tid = threadIdx.x;
    int lane = tid & 63, wave = tid >> 6;
    int row = lane & 15, quad = lane >> 4;
    int g = blockIdx.x * 4 + wave;             // M-tile id, 2048 total
    int r0 = g * 16;
    size_t base = (size_t)(r0 + row) * E_;
    const size_t zstride = (size_t)N_ * T_ * E_ / 4;   // f4 units

    h8 a[2];
#pragma unroll
    for (int half = 0; half < 2; half++) {
        f4 u0 = {0.f,0.f,0.f,0.f}, u1 = {0.f,0.f,0.f,0.f};
#pragma unroll
        for (int zz = 0; zz < 4; zz++) {
            const f4* p = reinterpret_cast<const f4*>(PO) + zz * zstride + base / 4;
            f4 w0 = p[half * 8 + quad * 2];
            f4 w1 = p[half * 8 + quad * 2 + 1];
#pragma unroll
            for (int i = 0; i < 4; i++) { u0[i] += w0[i]; u1[i] += w1[i]; }
        }
        union { h4 h[2]; h8 v; } pk;
        pk.h[0] = pack4_f16(u0[0], u0[1], u0[2], u0[3]);
        pk.h[1] = pack4_f16(u1[0], u1[1], u1[2], u1[3]);
        a[half] = pk.v;
    }
    f4 acc[4];
#pragma unroll
    for (int ne = 0; ne < 4; ne++) {
        const _Float16* wtb = Wt + (size_t)(ne * 16 + row) * 64;
        h8 b0 = *reinterpret_cast<const h8*>(wtb + quad * 8);
        h8 b1 = *reinterpret_cast<const h8*>(wtb + 32 + quad * 8);
        acc[ne] = __builtin_amdgcn_mfma_f32_16x16x32_f16(a[0], b0, (f4){0.f,0.f,0.f,0.f}, 0, 0, 0);
        acc[ne] = __builtin_amdgcn_mfma_f32_16x16x32_f16(a[1], b1, acc[ne], 0, 0, 0);
    }
#pragma unroll
    for (int ne = 0; ne < 4; ne++) {
        float bias = bfc[ne * 16 + row];
#pragma unroll
        for (int i = 0; i < 4; i++)
            out[(size_t)(r0 + quad * 4 + i) * E_ + ne * 16 + row] = acc[ne][i] + bias;
    }
}

extern "C" void kernel_launch(void* const* d_in, const int* in_sizes, int n_in,
                              void* d_out, int out_size, void* d_ws, size_t ws_size,
                              hipStream_t stream) {
    (void)in_sizes; (void)n_in; (void)out_size; (void)ws_size;
    const float* value = (const float*)d_in[0];
    const float* key   = (const float*)d_in[1];
    const float* query = (const float*)d_in[2];
    const float* Wq    = (const float*)d_in[3];
    const float* bq    = (const float*)d_in[4];
    const float* Wk    = (const float*)d_in[5];
    const float* bk    = (const float*)d_in[6];
    const float* Wv    = (const float*)d_in[7];
    const float* bv    = (const float*)d_in[8];
    const float* Wfc   = (const float*)d_in[9];
    const float* bfc   = (const float*)d_in[10];
    float* out = (float*)d_out;

    // ws bytes: Qh 0-4M | Kh 4-8M | Vt 8-12M | Wt 12M | Lp 13-15M | PO 15-47M
    char* ws = (char*)d_ws;
    _Float16* Qh  = (_Float16*)(ws);
    _Float16* Kh  = (_Float16*)(ws + (4u << 20));
    _Float16* Vt  = (_Float16*)(ws + (8u << 20));
    _Float16* Wt  = (_Float16*)(ws + (12u << 20));
    float*    Lp  = (float*)   (ws + (13u << 20));
    float*    PO  = (float*)   (ws + (15u << 20));

    proj_kernel<<<dim3(512, 4), 256, 0, stream>>>(
        query, Wq, bq, key, Wk, bk, value, Wv, bv, Wfc, Qh, Kh, Vt, Wt);
    stats_kernel<<<dim3(NH_, 8, 4), 256, 0, stream>>>(Qh, Kh, Lp);
    attn_kernel<<<dim3(NH_, 8, 4), 256, 0, stream>>>(Qh, Kh, Vt, Lp, PO);
    fc_kernel<<<512, 256, 0, stream>>>(PO, Wt, bfc, out);
}